// Round 16
// baseline (62.964 us; speedup 1.0000x reference)
//
#include <hip/hip_runtime.h>

typedef __attribute__((ext_vector_type(8))) _Float16 f16x8;
typedef __attribute__((ext_vector_type(4))) _Float16 f16x4;
typedef __attribute__((ext_vector_type(4))) float   f32x4;

#define BATCH 16384
#define NFEAT 512
#define NCLS  1000
#define NLEAF 256
#define NINT  255
#define LDP   72    // A-staging LDS row stride (f16), 144B: 2-way banks on frag reads
#define PSTR  257   // P LDS row stride (f32)

// ---- gate_w (255x512) f32 -> gwF f16 in MFMA-B-fragment layout, padded to 256 rows ----
// fragment pair p = c16*16 + ks; gwF[(p*64+lane)*8+j] = W[c16*16+(lane&15)][ks*32+(lane>>4)*8+j]
__global__ __launch_bounds__(64) void cvt_gw(const float* __restrict__ gw,
                                             _Float16* __restrict__ gwF) {
  const int p = blockIdx.x;             // 256 pairs
  const int lane = threadIdx.x;         // 64
  const int c = (p >> 4) * 16 + (lane & 15);
  const int k0 = (p & 15) * 32 + (lane >> 4) * 8;
  f16x8 o = {};
  if (c < NINT) {
    float4 v0 = *(const float4*)&gw[(size_t)c * NFEAT + k0];
    float4 v1 = *(const float4*)&gw[(size_t)c * NFEAT + k0 + 4];
    o[0] = (_Float16)v0.x; o[1] = (_Float16)v0.y;
    o[2] = (_Float16)v0.z; o[3] = (_Float16)v0.w;
    o[4] = (_Float16)v1.x; o[5] = (_Float16)v1.y;
    o[6] = (_Float16)v1.z; o[7] = (_Float16)v1.w;
  }
  *(f16x8*)&gwF[((size_t)p * 64 + lane) * 8] = o;   // 16B/lane contiguous
}

// ---- softmax of leaf_logits rows -> distF in MFMA-fragment-swizzled layout ----
__global__ __launch_bounds__(256) void softmax_t(const float* __restrict__ L,
                                                 _Float16* __restrict__ distF) {
  __shared__ float red[4];
  const int l = blockIdx.x, t = threadIdx.x;
  const int wave = t >> 6, lane = t & 63;
  const int kt = l >> 5, lhi_l = (l >> 3) & 3, jj = l & 7;
  float v[4];
  const bool live = t < 250;
  if (live) {
    float4 f = *(const float4*)&L[(size_t)l * NCLS + t * 4];
    v[0] = f.x; v[1] = f.y; v[2] = f.z; v[3] = f.w;
  } else {
    v[0] = v[1] = v[2] = v[3] = -1e30f;
  }
  float mx = fmaxf(fmaxf(v[0], v[1]), fmaxf(v[2], v[3]));
#pragma unroll
  for (int s = 32; s; s >>= 1) mx = fmaxf(mx, __shfl_xor(mx, s));
  if (lane == 0) red[wave] = mx;
  __syncthreads();
  mx = fmaxf(fmaxf(red[0], red[1]), fmaxf(red[2], red[3]));
  __syncthreads();
  float e[4], sum = 0.f;
#pragma unroll
  for (int i = 0; i < 4; ++i) { e[i] = __expf(v[i] - mx); sum += e[i]; }
  if (!live) { e[0] = e[1] = e[2] = e[3] = 0.f; sum = 0.f; }
#pragma unroll
  for (int s = 32; s; s >>= 1) sum += __shfl_xor(sum, s);
  if (lane == 0) red[wave] = sum;
  __syncthreads();
  sum = red[0] + red[1] + red[2] + red[3];
  float inv = 1.f / sum;
#pragma unroll
  for (int i = 0; i < 4; ++i) {
    int c = t * 4 + i;
    float val = live ? e[i] * inv : 0.f;
    int c16 = c >> 4, ln = c & 15;
    size_t idx = (((size_t)(c16 * 8 + kt)) * 64 + lhi_l * 16 + ln) * 8 + jj;
    distF[idx] = (_Float16)val;
  }
}

// ---- kernel 1: gemm1 + sigmoid + tree -> muFg (global, fragment layout) ----
// BM=64, 256 blocks (1/CU), 512 threads (8 waves, 2x4).
// A double-buffered in LDS -> ONE barrier per K-step; B fragment-direct from L2 (gwF).
__global__ __launch_bounds__(512)
void g1mu(const float* __restrict__ x, const _Float16* __restrict__ gwF,
          const float* __restrict__ gb, _Float16* __restrict__ muFg) {
  __shared__ union {
    _Float16 A[2][64 * LDP];   // 18,432 B (double-buffered A tile)
    float P[64 * PSTR];        // 65,792 B
  } sm;

  const int tid  = threadIdx.x;
  const int wave = tid >> 6, lane = tid & 63;
  const int ln15 = lane & 15, lhi = lane >> 4;
  const int wr = wave >> 2, wc = wave & 3;      // 2x4 waves: 32 rows x 64 cols
  const int r0 = blockIdx.x * 64;

  // ---------------- phase 1: logits = x @ W^T ----------------
  f32x4 acc1[2][4] = {};
  const int arow = tid >> 4, acol = (tid & 15) * 4;  // 2 float4/thread (rows 0..31, 32..63)

  float4 pa, pa2;

#define P1_LOAD(k0)                                                              \
  {                                                                              \
    pa  = *(const float4*)&x[(size_t)(r0 + arow) * NFEAT + (k0) + acol];         \
    pa2 = *(const float4*)&x[(size_t)(r0 + 32 + arow) * NFEAT + (k0) + acol];    \
  }
#define P1_WRITE(buf)                                                            \
  {                                                                              \
    f16x4 h;                                                                     \
    h[0] = (_Float16)pa.x; h[1] = (_Float16)pa.y;                                \
    h[2] = (_Float16)pa.z; h[3] = (_Float16)pa.w;                                \
    *(f16x4*)&sm.A[buf][arow * LDP + acol] = h;                                  \
    h[0] = (_Float16)pa2.x; h[1] = (_Float16)pa2.y;                              \
    h[2] = (_Float16)pa2.z; h[3] = (_Float16)pa2.w;                              \
    *(f16x4*)&sm.A[buf][(32 + arow) * LDP + acol] = h;                           \
  }

  P1_LOAD(0);
  P1_WRITE(0);
  __syncthreads();
  for (int k = 0; k < NFEAT / 64; ++k) {
    if (k < NFEAT / 64 - 1) P1_LOAD((k + 1) * 64);   // loads fly over compute
#pragma unroll
    for (int kk = 0; kk < 2; ++kk) {
      f16x8 a[2];
#pragma unroll
      for (int m = 0; m < 2; ++m)
        a[m] = *(const f16x8*)&sm.A[k & 1][(wr * 32 + m * 16 + ln15) * LDP + kk * 32 + lhi * 8];
#pragma unroll
      for (int n = 0; n < 4; ++n) {
        // B fragment straight from L2: 64 lanes x 16B = 1KB contiguous
        f16x8 b = *(const f16x8*)&gwF[(((size_t)(wc * 4 + n) * 16 + k * 2 + kk) * 64 + lane) * 8];
        acc1[0][n] = __builtin_amdgcn_mfma_f32_16x16x32_f16(a[0], b, acc1[0][n], 0, 0, 0);
        acc1[1][n] = __builtin_amdgcn_mfma_f32_16x16x32_f16(a[1], b, acc1[1][n], 0, 0, 0);
      }
    }
    // write NEXT tile into the other buffer: its prior readers finished at bar(k-1)
    if (k < NFEAT / 64 - 1) P1_WRITE((k + 1) & 1);
    __syncthreads();                               // one barrier per K-step
  }

  // ---------------- phase 2a: sigmoid -> P (LDS, stride 257) ----------------
#pragma unroll
  for (int m = 0; m < 2; ++m)
#pragma unroll
    for (int n = 0; n < 4; ++n) {
      int col = wc * 64 + n * 16 + ln15;
      float bb = (col < NINT) ? gb[col] : 0.f;
#pragma unroll
      for (int j = 0; j < 4; ++j) {
        int rl = wr * 32 + m * 16 + lhi * 4 + j;
        float v = acc1[m][n][j] + bb;
        sm.P[rl * PSTR + col] = 1.f / (1.f + __expf(-v));
      }
    }
  __syncthreads();

  // ---------------- phase 2b: tree product -> muFg (global, fragment layout) ----------------
  const int lf   = lane * 4;
  const int g_hi = lane >> 3;            // k-tile index (leaf>>5)
  const int sub  = ((lane >> 1) & 3) * 16;
  const int j4   = (lane & 1) * 4;
#pragma unroll
  for (int rr = 0; rr < 8; ++rr) {
    int row = wave * 8 + rr;             // 8 waves x 8 = 64 rows
    const float* p = &sm.P[row * PSTR];
    float pre = 1.f;
#pragma unroll
    for (int d = 0; d < 6; ++d) {
      int node = (1 << d) - 1 + (lf >> (8 - d));
      int bit  = (lf >> (7 - d)) & 1;
      float g = p[node];
      pre *= bit ? g : (1.f - g);
    }
    float g6  = p[63 + lane];
    float g7a = p[127 + 2 * lane];
    float g7b = p[128 + 2 * lane];
    f16x4 o;
    o[0] = (_Float16)(pre * (1.f - g6) * (1.f - g7a));
    o[1] = (_Float16)(pre * (1.f - g6) * g7a);
    o[2] = (_Float16)(pre * g6 * (1.f - g7b));
    o[3] = (_Float16)(pre * g6 * g7b);
    int row_g = r0 + row;
    size_t idx = (((size_t)(row_g >> 4) * 8 + g_hi) * 64 + sub + (row_g & 15)) * 8 + j4;
    *(f16x4*)&muFg[idx] = o;
  }
#undef P1_LOAD
#undef P1_WRITE
}

// ---- kernel 2: out = mu @ dist^T. No LDS, fragment loads, high occupancy ----
// grid (256 row-blocks x 8 col-strips), 256 threads (4 waves).
__global__ __launch_bounds__(256)
void g2(const _Float16* __restrict__ muFg, const _Float16* __restrict__ distF,
        float* __restrict__ out) {
  const int tid  = threadIdx.x;
  const int wave = tid >> 6, lane = tid & 63;
  const int ln15 = lane & 15, lhi = lane >> 4;
  const int row16 = blockIdx.x * 4 + wave;     // 16-row group
  const int cs    = blockIdx.y;                // 128-col strip

  f16x8 aa[8];
#pragma unroll
  for (int kk = 0; kk < 8; ++kk)               // 1KB contiguous per load
    aa[kk] = *(const f16x8*)&muFg[(((size_t)row16 * 8 + kk) * 64 + lane) * 8];

  const int rb = row16 * 16 + lhi * 4;
  for (int ct = 0; ct < 8; ++ct) {
    const int c16 = cs * 8 + ct;
    f32x4 acc = {};
#pragma unroll
    for (int kk = 0; kk < 8; ++kk) {
      f16x8 bb = *(const f16x8*)&distF[(((size_t)c16 * 8 + kk) * 64 + lane) * 8];
      acc = __builtin_amdgcn_mfma_f32_16x16x32_f16(aa[kk], bb, acc, 0, 0, 0);
    }
    const int col = c16 * 16 + ln15;
    if (col < NCLS) {
#pragma unroll
      for (int j = 0; j < 4; ++j)
        out[(size_t)(rb + j) * NCLS + col] = acc[j];
    }
  }
}

extern "C" void kernel_launch(void* const* d_in, const int* in_sizes, int n_in,
                              void* d_out, int out_size, void* d_ws, size_t ws_size,
                              hipStream_t stream) {
  const float* x  = (const float*)d_in[0];   // 16384x512
  const float* gw = (const float*)d_in[1];   // 255x512
  const float* gb = (const float*)d_in[2];   // 255
  const float* ll = (const float*)d_in[3];   // 256x1000
  float* out = (float*)d_out;                // 16384x1000
  char* ws = (char*)d_ws;

  _Float16* gwF   = (_Float16*)(ws);             // 262,144 B (fragment layout)
  _Float16* distF = (_Float16*)(ws + 262144);    // 524,288 B (fragment layout)
  _Float16* muFg  = (_Float16*)(ws + 786432);    // 8,388,608 B (fragment layout)

  cvt_gw   <<<256, 64,  0, stream>>>(gw, gwF);
  softmax_t<<<256, 256, 0, stream>>>(ll, distF);
  g1mu     <<<BATCH / 64, 512, 0, stream>>>(x, gwF, gb, muFg);
  g2       <<<dim3(BATCH / 64, 8), 256, 0, stream>>>(muFg, distF, out);
}